// Round 1
// baseline (1156.047 us; speedup 1.0000x reference)
//
#include <hip/hip_runtime.h>
#include <math.h>

#define NUM_USERS  100000
#define NUM_ITEMS  50000
#define N_NODES    150000
#define EMBED_DIM  64
#define NUM_EDGES  1250000
#define MLP_HID    32

// ---------------------------------------------------------------------------
// Kernel 1: per-edge MLP  ef(8) -> relu(32) -> sigmoid(1), plus deg atomicAdd
// ---------------------------------------------------------------------------
__global__ void edge_mlp_deg(const float* __restrict__ edge_attr,
                             const float* __restrict__ ew,
                             const float* __restrict__ w1,
                             const float* __restrict__ b1,
                             const float* __restrict__ w2,
                             const float* __restrict__ b2,
                             const int*   __restrict__ edge_index,
                             float* __restrict__ w_out,
                             float* __restrict__ deg) {
    __shared__ float w1s[8 * MLP_HID];
    __shared__ float b1s[MLP_HID];
    __shared__ float w2s[MLP_HID];
    int tid = threadIdx.x;
    if (tid < 8 * MLP_HID) w1s[tid] = w1[tid];
    if (tid < MLP_HID) { b1s[tid] = b1[tid]; w2s[tid] = w2[tid]; }
    __syncthreads();

    int e = blockIdx.x * blockDim.x + tid;
    if (e >= NUM_EDGES) return;

    float ef[8];
#pragma unroll
    for (int k = 0; k < 7; ++k) ef[k] = edge_attr[e * 7 + k];
    ef[7] = ew[e];

    float s = b2[0];
#pragma unroll
    for (int j = 0; j < MLP_HID; ++j) {
        float h = b1s[j];
#pragma unroll
        for (int k = 0; k < 8; ++k) h = fmaf(ef[k], w1s[k * MLP_HID + j], h);
        h = fmaxf(h, 0.0f);
        s = fmaf(h, w2s[j], s);
    }
    float w = 1.0f / (1.0f + expf(-s));
    w_out[e] = w;
    int c = edge_index[NUM_EDGES + e];
    atomicAdd(&deg[c], w);
}

// ---------------------------------------------------------------------------
// Kernel 2: deg -> dinv in place
// ---------------------------------------------------------------------------
__global__ void deg_to_dinv(float* __restrict__ deg) {
    int i = blockIdx.x * blockDim.x + threadIdx.x;
    if (i >= N_NODES) return;
    float d = deg[i];
    deg[i] = (d > 0.0f) ? rsqrtf(fmaxf(d, 1e-30f)) : 0.0f;
}

// ---------------------------------------------------------------------------
// Kernel 3: norm[e] = dinv[row]*w[e]*dinv[col]  (in place over w buffer)
// ---------------------------------------------------------------------------
__global__ void edge_norm(const int* __restrict__ edge_index,
                          const float* __restrict__ dinv,
                          float* __restrict__ w) {
    int e = blockIdx.x * blockDim.x + threadIdx.x;
    if (e >= NUM_EDGES) return;
    int r = edge_index[e];
    int c = edge_index[NUM_EDGES + e];
    w[e] = dinv[r] * w[e] * dinv[c];
}

// ---------------------------------------------------------------------------
// Kernel 4: build x0 (l2norm rows), acc = x0.  One 64-lane wave per row.
// ---------------------------------------------------------------------------
__global__ void init_x(const float* __restrict__ user_w,
                       const float* __restrict__ artist_w,
                       const float* __restrict__ album_w,
                       const float* __restrict__ audio,
                       const int*   __restrict__ artist_ids,
                       const int*   __restrict__ album_ids,
                       float* __restrict__ x,
                       float* __restrict__ acc) {
    int t = blockIdx.x * blockDim.x + threadIdx.x;
    int row = t >> 6;
    int lane = t & 63;
    if (row >= N_NODES) return;

    float v;
    if (row < NUM_USERS) {
        v = user_w[row * EMBED_DIM + lane];
    } else {
        int r = row - NUM_USERS;
        int ar = artist_ids[r];
        int al = album_ids[r];
        v = audio[r * EMBED_DIM + lane]
          + 0.5f * (artist_w[ar * EMBED_DIM + lane] + album_w[al * EMBED_DIM + lane]);
    }
    float ss = v * v;
#pragma unroll
    for (int off = 32; off > 0; off >>= 1) ss += __shfl_xor(ss, off);
    float scale = 1.0f / fmaxf(sqrtf(ss), 1e-12f);
    float o = v * scale;
    x[row * EMBED_DIM + lane] = o;
    acc[row * EMBED_DIM + lane] = o;
}

// ---------------------------------------------------------------------------
// Kernel 5: one propagation layer, scatter-atomic.
// lane d of edge e: xout[col*64+d] += norm[e] * xin[row*64+d]
// ---------------------------------------------------------------------------
__global__ void propagate(const int* __restrict__ edge_index,
                          const float* __restrict__ norm,
                          const float* __restrict__ xin,
                          float* __restrict__ xout) {
    int t = blockIdx.x * blockDim.x + threadIdx.x;
    int e = t >> 6;
    int lane = t & 63;
    if (e >= NUM_EDGES) return;
    float n = norm[e];
    int r = edge_index[e];
    int c = edge_index[NUM_EDGES + e];
    float v = n * xin[r * EMBED_DIM + lane];
    atomicAdd(&xout[c * EMBED_DIM + lane], v);
}

// ---------------------------------------------------------------------------
// Kernel 6: acc += x  (float4)
// ---------------------------------------------------------------------------
__global__ void acc_add(float* __restrict__ acc, const float* __restrict__ x) {
    int i = blockIdx.x * blockDim.x + threadIdx.x;
    if (i >= (N_NODES * EMBED_DIM) / 4) return;
    float4 a = ((const float4*)acc)[i];
    float4 b = ((const float4*)x)[i];
    a.x += b.x; a.y += b.y; a.z += b.z; a.w += b.w;
    ((float4*)acc)[i] = a;
}

// ---------------------------------------------------------------------------
// Kernel 7: out = l2norm(acc/4) in place; set align_loss scalar.
// ---------------------------------------------------------------------------
__global__ void finalize(float* __restrict__ acc) {
    int t = blockIdx.x * blockDim.x + threadIdx.x;
    int row = t >> 6;
    int lane = t & 63;
    if (row >= N_NODES) return;
    float v = acc[row * EMBED_DIM + lane] * 0.25f;
    float ss = v * v;
#pragma unroll
    for (int off = 32; off > 0; off >>= 1) ss += __shfl_xor(ss, off);
    float scale = 1.0f / fmaxf(sqrtf(ss), 1e-12f);
    acc[row * EMBED_DIM + lane] = v * scale;
    if (t == 0) acc[N_NODES * EMBED_DIM] = 0.0f;  // align_loss
}

// ---------------------------------------------------------------------------
extern "C" void kernel_launch(void* const* d_in, const int* in_sizes, int n_in,
                              void* d_out, int out_size, void* d_ws, size_t ws_size,
                              hipStream_t stream) {
    const float* user_w     = (const float*)d_in[0];
    const float* artist_w   = (const float*)d_in[1];
    const float* album_w    = (const float*)d_in[2];
    const float* audio      = (const float*)d_in[3];
    const float* edge_attr  = (const float*)d_in[4];
    const float* ew         = (const float*)d_in[5];
    const float* w1         = (const float*)d_in[6];
    const float* b1         = (const float*)d_in[7];
    const float* w2         = (const float*)d_in[8];
    const float* b2         = (const float*)d_in[9];
    const int*   edge_index = (const int*)d_in[10];
    const int*   artist_ids = (const int*)d_in[11];
    const int*   album_ids  = (const int*)d_in[12];
    float* out = (float*)d_out;

    float* ws    = (float*)d_ws;
    float* normw = ws;                 // NUM_EDGES      floats
    float* deg   = ws + 1250000;       // N_NODES        floats
    float* xa    = ws + 1400000;       // 9,600,000      floats
    float* xb    = ws + 11000000;      // 9,600,000      floats

    const int B = 256;

    // deg = 0
    hipMemsetAsync(deg, 0, N_NODES * sizeof(float), stream);

    // edge MLP + deg accumulation
    edge_mlp_deg<<<(NUM_EDGES + B - 1) / B, B, 0, stream>>>(
        edge_attr, ew, w1, b1, w2, b2, edge_index, normw, deg);

    // dinv
    deg_to_dinv<<<(N_NODES + B - 1) / B, B, 0, stream>>>(deg);

    // norm
    edge_norm<<<(NUM_EDGES + B - 1) / B, B, 0, stream>>>(edge_index, deg, normw);

    // x0 + acc init (acc lives in d_out)
    init_x<<<(N_NODES * EMBED_DIM) / B, B, 0, stream>>>(
        user_w, artist_w, album_w, audio, artist_ids, album_ids, xa, out);

    float* xcur = xa;
    float* xnew = xb;
    for (int layer = 0; layer < 3; ++layer) {
        hipMemsetAsync(xnew, 0, (size_t)N_NODES * EMBED_DIM * sizeof(float), stream);
        propagate<<<(NUM_EDGES * EMBED_DIM) / B, B, 0, stream>>>(
            edge_index, normw, xcur, xnew);
        acc_add<<<((N_NODES * EMBED_DIM) / 4 + B - 1) / B, B, 0, stream>>>(out, xnew);
        float* tmp = xcur; xcur = xnew; xnew = tmp;
    }

    finalize<<<(N_NODES * EMBED_DIM) / B, B, 0, stream>>>(out);
}

// Round 2
// 999.250 us; speedup vs baseline: 1.1569x; 1.1569x over previous
//
#include <hip/hip_runtime.h>
#include <math.h>

#define NUM_USERS  100000
#define NUM_ITEMS  50000
#define N_NODES    150000
#define EMBED_DIM  64
#define NUM_EDGES  1250000
#define MLP_HID    32

// ---------------------------------------------------------------------------
// Kernel 1: per-edge MLP  ef(8) -> relu(32) -> sigmoid(1), plus deg (float)
// and count (int) atomics on col.  deg/cnt are small (0.6 MB) -> L2-resident.
// ---------------------------------------------------------------------------
__global__ void edge_mlp_deg(const float* __restrict__ edge_attr,
                             const float* __restrict__ ew,
                             const float* __restrict__ w1,
                             const float* __restrict__ b1,
                             const float* __restrict__ w2,
                             const float* __restrict__ b2,
                             const int*   __restrict__ edge_index,
                             float* __restrict__ w_out,
                             float* __restrict__ deg,
                             int*   __restrict__ cnt) {
    __shared__ float w1s[8 * MLP_HID];
    __shared__ float b1s[MLP_HID];
    __shared__ float w2s[MLP_HID];
    int tid = threadIdx.x;
    if (tid < 8 * MLP_HID) w1s[tid] = w1[tid];
    if (tid < MLP_HID) { b1s[tid] = b1[tid]; w2s[tid] = w2[tid]; }
    __syncthreads();

    int e = blockIdx.x * blockDim.x + tid;
    if (e >= NUM_EDGES) return;

    float ef[8];
#pragma unroll
    for (int k = 0; k < 7; ++k) ef[k] = edge_attr[e * 7 + k];
    ef[7] = ew[e];

    float s = b2[0];
#pragma unroll
    for (int j = 0; j < MLP_HID; ++j) {
        float h = b1s[j];
#pragma unroll
        for (int k = 0; k < 8; ++k) h = fmaf(ef[k], w1s[k * MLP_HID + j], h);
        h = fmaxf(h, 0.0f);
        s = fmaf(h, w2s[j], s);
    }
    float w = 1.0f / (1.0f + expf(-s));
    w_out[e] = w;
    int c = edge_index[NUM_EDGES + e];
    atomicAdd(&deg[c], w);
    atomicAdd(&cnt[c], 1);
}

// ---------------------------------------------------------------------------
// Kernel 2: deg -> dinv in place
// ---------------------------------------------------------------------------
__global__ void deg_to_dinv(float* __restrict__ deg) {
    int i = blockIdx.x * blockDim.x + threadIdx.x;
    if (i >= N_NODES) return;
    float d = deg[i];
    deg[i] = (d > 0.0f) ? rsqrtf(fmaxf(d, 1e-30f)) : 0.0f;
}

// ---------------------------------------------------------------------------
// Kernel 3: exclusive scan of cnt[150000] -> row_ptr[150001], cursor copy.
// Single block, 1024 threads, ~147 elements per thread.
// ---------------------------------------------------------------------------
__global__ void scan_counts(const int* __restrict__ cnt,
                            int* __restrict__ row_ptr,
                            int* __restrict__ cursor) {
    __shared__ int s[1024];
    int tid = threadIdx.x;
    const int CH = (N_NODES + 1023) / 1024;  // 147
    int base = tid * CH;
    int lim = base + CH; if (lim > N_NODES) lim = N_NODES;

    int sum = 0;
    for (int i = base; i < lim; ++i) sum += cnt[i];
    s[tid] = sum;
    __syncthreads();
    // Hillis-Steele inclusive scan over 1024 partial sums
    for (int off = 1; off < 1024; off <<= 1) {
        int v = (tid >= off) ? s[tid - off] : 0;
        __syncthreads();
        s[tid] += v;
        __syncthreads();
    }
    int run = s[tid] - sum;  // exclusive prefix of this chunk
    for (int i = base; i < lim; ++i) {
        row_ptr[i] = run;
        cursor[i]  = run;
        run += cnt[i];
    }
    if (tid == 1023) row_ptr[N_NODES] = s[1023];
}

// ---------------------------------------------------------------------------
// Kernel 4: bucket scatter into CSR (sorted by col), fusing the edge norm:
// csr_w = dinv[row] * w * dinv[col]
// ---------------------------------------------------------------------------
__global__ void csr_scatter(const int* __restrict__ edge_index,
                            const float* __restrict__ w,
                            const float* __restrict__ dinv,
                            int* __restrict__ cursor,
                            int* __restrict__ csr_src,
                            float* __restrict__ csr_w) {
    int e = blockIdx.x * blockDim.x + threadIdx.x;
    if (e >= NUM_EDGES) return;
    int r = edge_index[e];
    int c = edge_index[NUM_EDGES + e];
    int pos = atomicAdd(&cursor[c], 1);
    csr_src[pos] = r;
    csr_w[pos] = dinv[r] * w[e] * dinv[c];
}

// ---------------------------------------------------------------------------
// Kernel 5: build x0 (l2norm rows), acc = x0.  One 64-lane wave per row.
// ---------------------------------------------------------------------------
__global__ void init_x(const float* __restrict__ user_w,
                       const float* __restrict__ artist_w,
                       const float* __restrict__ album_w,
                       const float* __restrict__ audio,
                       const int*   __restrict__ artist_ids,
                       const int*   __restrict__ album_ids,
                       float* __restrict__ x,
                       float* __restrict__ acc) {
    int t = blockIdx.x * blockDim.x + threadIdx.x;
    int row = t >> 6;
    int lane = t & 63;
    if (row >= N_NODES) return;

    float v;
    if (row < NUM_USERS) {
        v = user_w[row * EMBED_DIM + lane];
    } else {
        int r = row - NUM_USERS;
        int ar = artist_ids[r];
        int al = album_ids[r];
        v = audio[r * EMBED_DIM + lane]
          + 0.5f * (artist_w[ar * EMBED_DIM + lane] + album_w[al * EMBED_DIM + lane]);
    }
    float ss = v * v;
#pragma unroll
    for (int off = 32; off > 0; off >>= 1) ss += __shfl_xor(ss, off);
    float scale = 1.0f / fmaxf(sqrtf(ss), 1e-12f);
    float o = v * scale;
    x[row * EMBED_DIM + lane] = o;
    acc[row * EMBED_DIM + lane] = o;
}

// ---------------------------------------------------------------------------
// Kernel 6: pull-mode propagation. One wave per node; lane = embed dim.
// Lanes cooperatively load up to 64 (src, norm) pairs, then broadcast each
// via readlane-style shuffles; gather x[src] rows coalesced (256 B/wave).
// Epilogue fuses acc += x_new; FINAL layer fuses l2norm(acc/4) into d_out.
// ---------------------------------------------------------------------------
template <bool FINAL>
__global__ void propagate_pull(const int* __restrict__ row_ptr,
                               const int* __restrict__ csr_src,
                               const float* __restrict__ csr_w,
                               const float* __restrict__ xin,
                               float* __restrict__ xout,
                               float* __restrict__ acc) {
    int t = blockIdx.x * blockDim.x + threadIdx.x;
    int node = t >> 6;
    int lane = t & 63;
    if (node >= N_NODES) return;

    int start = row_ptr[node];
    int end   = row_ptr[node + 1];

    float a = 0.0f;
    for (int base = start; base < end; base += 64) {
        int j = base + lane;
        int src = 0;
        float nw = 0.0f;
        if (j < end) { src = csr_src[j]; nw = csr_w[j]; }
        int cnt = end - base; if (cnt > 64) cnt = 64;
        for (int tt = 0; tt < cnt; ++tt) {
            int s = __shfl(src, tt);
            float n = __shfl(nw, tt);
            a = fmaf(n, xin[(size_t)s * EMBED_DIM + lane], a);
        }
    }

    size_t o = (size_t)node * EMBED_DIM + lane;
    if (FINAL) {
        float v = (acc[o] + a) * 0.25f;
        float ss = v * v;
#pragma unroll
        for (int off = 32; off > 0; off >>= 1) ss += __shfl_xor(ss, off);
        float scale = 1.0f / fmaxf(sqrtf(ss), 1e-12f);
        acc[o] = v * scale;
        if (blockIdx.x == 0 && threadIdx.x == 0)
            acc[(size_t)N_NODES * EMBED_DIM] = 0.0f;  // align_loss
    } else {
        xout[o] = a;
        acc[o] = acc[o] + a;
    }
}

// ---------------------------------------------------------------------------
extern "C" void kernel_launch(void* const* d_in, const int* in_sizes, int n_in,
                              void* d_out, int out_size, void* d_ws, size_t ws_size,
                              hipStream_t stream) {
    const float* user_w     = (const float*)d_in[0];
    const float* artist_w   = (const float*)d_in[1];
    const float* album_w    = (const float*)d_in[2];
    const float* audio      = (const float*)d_in[3];
    const float* edge_attr  = (const float*)d_in[4];
    const float* ew         = (const float*)d_in[5];
    const float* w1         = (const float*)d_in[6];
    const float* b1         = (const float*)d_in[7];
    const float* w2         = (const float*)d_in[8];
    const float* b2         = (const float*)d_in[9];
    const int*   edge_index = (const int*)d_in[10];
    const int*   artist_ids = (const int*)d_in[11];
    const int*   album_ids  = (const int*)d_in[12];
    float* out = (float*)d_out;

    float* ws = (float*)d_ws;
    // Persistent regions:
    float* xa      = ws;                        // 9.6M floats
    float* xb      = ws + 9600000;              // 9.6M floats
    int*   row_ptr = (int*)(ws + 19200000);     // 150001 ints
    int*   csr_src = (int*)(ws + 19360000);     // 1.25M ints
    float* csr_w   = ws + 20610000;             // 1.25M floats
    // Transient regions aliased into xa (all dead before init_x writes xa):
    float* normw  = ws;                         // 1.25M floats (MLP weight out)
    float* deg    = ws + 1250000;               // 150k floats -> dinv in place
    int*   cnt    = (int*)(ws + 1400000);       // 150k ints
    int*   cursor = (int*)(ws + 1550000);       // 150k ints

    const int B = 256;

    // deg = 0, cnt = 0 (adjacent -> one memset)
    hipMemsetAsync(deg, 0, 2 * N_NODES * sizeof(float), stream);

    edge_mlp_deg<<<(NUM_EDGES + B - 1) / B, B, 0, stream>>>(
        edge_attr, ew, w1, b1, w2, b2, edge_index, normw, deg, cnt);

    deg_to_dinv<<<(N_NODES + B - 1) / B, B, 0, stream>>>(deg);

    scan_counts<<<1, 1024, 0, stream>>>(cnt, row_ptr, cursor);

    csr_scatter<<<(NUM_EDGES + B - 1) / B, B, 0, stream>>>(
        edge_index, normw, deg, cursor, csr_src, csr_w);

    init_x<<<(N_NODES * EMBED_DIM) / B, B, 0, stream>>>(
        user_w, artist_w, album_w, audio, artist_ids, album_ids, xa, out);

    const int pgrid = (N_NODES * EMBED_DIM) / B;  // 4 nodes per 256-thread block
    propagate_pull<false><<<pgrid, B, 0, stream>>>(row_ptr, csr_src, csr_w, xa, xb, out);
    propagate_pull<false><<<pgrid, B, 0, stream>>>(row_ptr, csr_src, csr_w, xb, xa, out);
    propagate_pull<true ><<<pgrid, B, 0, stream>>>(row_ptr, csr_src, csr_w, xa, xb, out);
}

// Round 3
// 667.545 us; speedup vs baseline: 1.7318x; 1.4969x over previous
//
#include <hip/hip_runtime.h>
#include <math.h>

#define NUM_USERS  100000
#define NUM_ITEMS  50000
#define N_NODES    150000
#define EMBED_DIM  64
#define NUM_EDGES  1250000
#define MLP_HID    32
#define SCAN_B     1024
#define SCAN_NB    ((N_NODES + SCAN_B - 1) / SCAN_B)   // 147

// ---------------------------------------------------------------------------
// Kernel 1: per-edge MLP  ef(8) -> relu(32) -> sigmoid(1), plus deg (float)
// and count (int) atomics on col.  deg/cnt are small (0.6 MB) -> L2-resident.
// ---------------------------------------------------------------------------
__global__ void edge_mlp_deg(const float* __restrict__ edge_attr,
                             const float* __restrict__ ew,
                             const float* __restrict__ w1,
                             const float* __restrict__ b1,
                             const float* __restrict__ w2,
                             const float* __restrict__ b2,
                             const int*   __restrict__ edge_index,
                             float* __restrict__ w_out,
                             float* __restrict__ deg,
                             int*   __restrict__ cnt) {
    __shared__ float w1s[8 * MLP_HID];
    __shared__ float b1s[MLP_HID];
    __shared__ float w2s[MLP_HID];
    int tid = threadIdx.x;
    if (tid < 8 * MLP_HID) w1s[tid] = w1[tid];
    if (tid < MLP_HID) { b1s[tid] = b1[tid]; w2s[tid] = w2[tid]; }
    __syncthreads();

    int e = blockIdx.x * blockDim.x + tid;
    if (e >= NUM_EDGES) return;

    float ef[8];
#pragma unroll
    for (int k = 0; k < 7; ++k) ef[k] = edge_attr[e * 7 + k];
    ef[7] = ew[e];

    float s = b2[0];
#pragma unroll
    for (int j = 0; j < MLP_HID; ++j) {
        float h = b1s[j];
#pragma unroll
        for (int k = 0; k < 8; ++k) h = fmaf(ef[k], w1s[k * MLP_HID + j], h);
        h = fmaxf(h, 0.0f);
        s = fmaf(h, w2s[j], s);
    }
    float w = 1.0f / (1.0f + expf(-s));
    w_out[e] = w;
    int c = edge_index[NUM_EDGES + e];
    atomicAdd(&deg[c], w);
    atomicAdd(&cnt[c], 1);
}

// ---------------------------------------------------------------------------
// Kernel 2: deg -> dinv in place
// ---------------------------------------------------------------------------
__global__ void deg_to_dinv(float* __restrict__ deg) {
    int i = blockIdx.x * blockDim.x + threadIdx.x;
    if (i >= N_NODES) return;
    float d = deg[i];
    deg[i] = (d > 0.0f) ? rsqrtf(fmaxf(d, 1e-30f)) : 0.0f;
}

// ---------------------------------------------------------------------------
// Device-wide exclusive scan of cnt -> row_ptr/cursor, 3 phases.
// ---------------------------------------------------------------------------
__global__ void scan_partial(const int* __restrict__ cnt,
                             int* __restrict__ part) {
    __shared__ int s[SCAN_B];
    int tid = threadIdx.x;
    int i = blockIdx.x * SCAN_B + tid;
    s[tid] = (i < N_NODES) ? cnt[i] : 0;
    __syncthreads();
#pragma unroll
    for (int off = SCAN_B / 2; off > 0; off >>= 1) {
        if (tid < off) s[tid] += s[tid + off];
        __syncthreads();
    }
    if (tid == 0) part[blockIdx.x] = s[0];
}

__global__ void scan_offsets(const int* __restrict__ part,
                             int* __restrict__ base_off,
                             int* __restrict__ row_ptr) {
    __shared__ int s[256];
    int tid = threadIdx.x;
    int v = (tid < SCAN_NB) ? part[tid] : 0;
    s[tid] = v;
    __syncthreads();
#pragma unroll
    for (int off = 1; off < 256; off <<= 1) {
        int t = (tid >= off) ? s[tid - off] : 0;
        __syncthreads();
        s[tid] += t;
        __syncthreads();
    }
    if (tid < SCAN_NB) base_off[tid] = s[tid] - v;   // exclusive
    if (tid == 255) row_ptr[N_NODES] = s[255];       // total
}

__global__ void scan_apply(const int* __restrict__ cnt,
                           const int* __restrict__ base_off,
                           int* __restrict__ row_ptr,
                           int* __restrict__ cursor) {
    __shared__ int s[SCAN_B];
    int tid = threadIdx.x;
    int i = blockIdx.x * SCAN_B + tid;
    int v = (i < N_NODES) ? cnt[i] : 0;
    s[tid] = v;
    __syncthreads();
    for (int off = 1; off < SCAN_B; off <<= 1) {
        int t = (tid >= off) ? s[tid - off] : 0;
        __syncthreads();
        s[tid] += t;
        __syncthreads();
    }
    if (i < N_NODES) {
        int excl = s[tid] - v + base_off[blockIdx.x];
        row_ptr[i] = excl;
        cursor[i]  = excl;
    }
}

// ---------------------------------------------------------------------------
// Kernel 4: bucket scatter into CSR (sorted by col), fusing the edge norm:
// csr_w = dinv[row] * w * dinv[col]
// ---------------------------------------------------------------------------
__global__ void csr_scatter(const int* __restrict__ edge_index,
                            const float* __restrict__ w,
                            const float* __restrict__ dinv,
                            int* __restrict__ cursor,
                            int* __restrict__ csr_src,
                            float* __restrict__ csr_w) {
    int e = blockIdx.x * blockDim.x + threadIdx.x;
    if (e >= NUM_EDGES) return;
    int r = edge_index[e];
    int c = edge_index[NUM_EDGES + e];
    int pos = atomicAdd(&cursor[c], 1);
    csr_src[pos] = r;
    csr_w[pos] = dinv[r] * w[e] * dinv[c];
}

// ---------------------------------------------------------------------------
// Kernel 5: build x0 (l2norm rows), acc = x0.  One 64-lane wave per row.
// ---------------------------------------------------------------------------
__global__ void init_x(const float* __restrict__ user_w,
                       const float* __restrict__ artist_w,
                       const float* __restrict__ album_w,
                       const float* __restrict__ audio,
                       const int*   __restrict__ artist_ids,
                       const int*   __restrict__ album_ids,
                       float* __restrict__ x,
                       float* __restrict__ acc) {
    int t = blockIdx.x * blockDim.x + threadIdx.x;
    int row = t >> 6;
    int lane = t & 63;
    if (row >= N_NODES) return;

    float v;
    if (row < NUM_USERS) {
        v = user_w[row * EMBED_DIM + lane];
    } else {
        int r = row - NUM_USERS;
        int ar = artist_ids[r];
        int al = album_ids[r];
        v = audio[r * EMBED_DIM + lane]
          + 0.5f * (artist_w[ar * EMBED_DIM + lane] + album_w[al * EMBED_DIM + lane]);
    }
    float ss = v * v;
#pragma unroll
    for (int off = 32; off > 0; off >>= 1) ss += __shfl_xor(ss, off);
    float scale = 1.0f / fmaxf(sqrtf(ss), 1e-12f);
    float o = v * scale;
    x[row * EMBED_DIM + lane] = o;
    acc[row * EMBED_DIM + lane] = o;
}

// ---------------------------------------------------------------------------
// Kernel 6: pull-mode propagation. One wave per node; lane = embed dim.
// ---------------------------------------------------------------------------
template <bool FINAL>
__global__ void propagate_pull(const int* __restrict__ row_ptr,
                               const int* __restrict__ csr_src,
                               const float* __restrict__ csr_w,
                               const float* __restrict__ xin,
                               float* __restrict__ xout,
                               float* __restrict__ acc) {
    int t = blockIdx.x * blockDim.x + threadIdx.x;
    int node = t >> 6;
    int lane = t & 63;
    if (node >= N_NODES) return;

    int start = row_ptr[node];
    int end   = row_ptr[node + 1];

    float a = 0.0f;
    for (int base = start; base < end; base += 64) {
        int j = base + lane;
        int src = 0;
        float nw = 0.0f;
        if (j < end) { src = csr_src[j]; nw = csr_w[j]; }
        int cnt = end - base; if (cnt > 64) cnt = 64;
        for (int tt = 0; tt < cnt; ++tt) {
            int s = __shfl(src, tt);
            float n = __shfl(nw, tt);
            a = fmaf(n, xin[(size_t)s * EMBED_DIM + lane], a);
        }
    }

    size_t o = (size_t)node * EMBED_DIM + lane;
    if (FINAL) {
        float v = (acc[o] + a) * 0.25f;
        float ss = v * v;
#pragma unroll
        for (int off = 32; off > 0; off >>= 1) ss += __shfl_xor(ss, off);
        float scale = 1.0f / fmaxf(sqrtf(ss), 1e-12f);
        acc[o] = v * scale;
        if (blockIdx.x == 0 && threadIdx.x == 0)
            acc[(size_t)N_NODES * EMBED_DIM] = 0.0f;  // align_loss
    } else {
        xout[o] = a;
        acc[o] = acc[o] + a;
    }
}

// ---------------------------------------------------------------------------
extern "C" void kernel_launch(void* const* d_in, const int* in_sizes, int n_in,
                              void* d_out, int out_size, void* d_ws, size_t ws_size,
                              hipStream_t stream) {
    const float* user_w     = (const float*)d_in[0];
    const float* artist_w   = (const float*)d_in[1];
    const float* album_w    = (const float*)d_in[2];
    const float* audio      = (const float*)d_in[3];
    const float* edge_attr  = (const float*)d_in[4];
    const float* ew         = (const float*)d_in[5];
    const float* w1         = (const float*)d_in[6];
    const float* b1         = (const float*)d_in[7];
    const float* w2         = (const float*)d_in[8];
    const float* b2         = (const float*)d_in[9];
    const int*   edge_index = (const int*)d_in[10];
    const int*   artist_ids = (const int*)d_in[11];
    const int*   album_ids  = (const int*)d_in[12];
    float* out = (float*)d_out;

    float* ws = (float*)d_ws;
    // Persistent regions:
    float* xa      = ws;                        // 9.6M floats
    float* xb      = ws + 9600000;              // 9.6M floats
    int*   row_ptr = (int*)(ws + 19200000);     // 150001 ints
    int*   csr_src = (int*)(ws + 19360000);     // 1.25M ints
    float* csr_w   = ws + 20610000;             // 1.25M floats
    // Transient regions aliased into xa (all dead before init_x writes xa):
    float* normw   = ws;                        // 1.25M floats (MLP weight out)
    float* deg     = ws + 1250000;              // 150k floats -> dinv in place
    int*   cnt     = (int*)(ws + 1400000);      // 150k ints
    int*   cursor  = (int*)(ws + 1550000);      // 150k ints
    int*   part    = (int*)(ws + 1700000);      // 147 ints
    int*   baseoff = (int*)(ws + 1701000);      // 147 ints

    const int B = 256;

    // deg = 0, cnt = 0 (adjacent -> one memset)
    hipMemsetAsync(deg, 0, 2 * N_NODES * sizeof(float), stream);

    edge_mlp_deg<<<(NUM_EDGES + B - 1) / B, B, 0, stream>>>(
        edge_attr, ew, w1, b1, w2, b2, edge_index, normw, deg, cnt);

    deg_to_dinv<<<(N_NODES + B - 1) / B, B, 0, stream>>>(deg);

    scan_partial<<<SCAN_NB, SCAN_B, 0, stream>>>(cnt, part);
    scan_offsets<<<1, 256, 0, stream>>>(part, baseoff, row_ptr);
    scan_apply<<<SCAN_NB, SCAN_B, 0, stream>>>(cnt, baseoff, row_ptr, cursor);

    csr_scatter<<<(NUM_EDGES + B - 1) / B, B, 0, stream>>>(
        edge_index, normw, deg, cursor, csr_src, csr_w);

    init_x<<<(N_NODES * EMBED_DIM) / B, B, 0, stream>>>(
        user_w, artist_w, album_w, audio, artist_ids, album_ids, xa, out);

    const int pgrid = (N_NODES * EMBED_DIM) / B;  // 4 nodes per 256-thread block
    propagate_pull<false><<<pgrid, B, 0, stream>>>(row_ptr, csr_src, csr_w, xa, xb, out);
    propagate_pull<false><<<pgrid, B, 0, stream>>>(row_ptr, csr_src, csr_w, xb, xa, out);
    propagate_pull<true ><<<pgrid, B, 0, stream>>>(row_ptr, csr_src, csr_w, xa, xb, out);
}

// Round 4
// 647.552 us; speedup vs baseline: 1.7853x; 1.0309x over previous
//
#include <hip/hip_runtime.h>
#include <math.h>

#define NUM_USERS  100000
#define NUM_ITEMS  50000
#define N_NODES    150000
#define EMBED_DIM  64
#define NUM_EDGES  1250000
#define MLP_HID    32
#define SCAN_B     1024
#define SCAN_NB    ((N_NODES + SCAN_B - 1) / SCAN_B)   // 147

// ---------------------------------------------------------------------------
// Kernel 1: per-edge MLP + col histogram (int atomics only; float deg atomic
// removed -> half the memory-side line-RMW traffic).
// ---------------------------------------------------------------------------
__global__ void edge_mlp_hist(const float* __restrict__ edge_attr,
                              const float* __restrict__ ew,
                              const float* __restrict__ w1,
                              const float* __restrict__ b1,
                              const float* __restrict__ w2,
                              const float* __restrict__ b2,
                              const int*   __restrict__ edge_index,
                              float* __restrict__ w_out,
                              int*   __restrict__ cnt) {
    __shared__ float w1s[8 * MLP_HID];
    __shared__ float b1s[MLP_HID];
    __shared__ float w2s[MLP_HID];
    int tid = threadIdx.x;
    if (tid < 8 * MLP_HID) w1s[tid] = w1[tid];
    if (tid < MLP_HID) { b1s[tid] = b1[tid]; w2s[tid] = w2[tid]; }
    __syncthreads();

    int e = blockIdx.x * blockDim.x + tid;
    if (e >= NUM_EDGES) return;

    float ef[8];
#pragma unroll
    for (int k = 0; k < 7; ++k) ef[k] = edge_attr[e * 7 + k];
    ef[7] = ew[e];

    float s = b2[0];
#pragma unroll
    for (int j = 0; j < MLP_HID; ++j) {
        float h = b1s[j];
#pragma unroll
        for (int k = 0; k < 8; ++k) h = fmaf(ef[k], w1s[k * MLP_HID + j], h);
        h = fmaxf(h, 0.0f);
        s = fmaf(h, w2s[j], s);
    }
    w_out[e] = 1.0f / (1.0f + expf(-s));
    int c = edge_index[NUM_EDGES + e];
    atomicAdd(&cnt[c], 1);
}

// ---------------------------------------------------------------------------
// Device-wide exclusive scan of cnt -> row_ptr/cursor, 3 phases.
// ---------------------------------------------------------------------------
__global__ void scan_partial(const int* __restrict__ cnt,
                             int* __restrict__ part) {
    __shared__ int s[SCAN_B];
    int tid = threadIdx.x;
    int i = blockIdx.x * SCAN_B + tid;
    s[tid] = (i < N_NODES) ? cnt[i] : 0;
    __syncthreads();
#pragma unroll
    for (int off = SCAN_B / 2; off > 0; off >>= 1) {
        if (tid < off) s[tid] += s[tid + off];
        __syncthreads();
    }
    if (tid == 0) part[blockIdx.x] = s[0];
}

__global__ void scan_offsets(const int* __restrict__ part,
                             int* __restrict__ base_off,
                             int* __restrict__ row_ptr) {
    __shared__ int s[256];
    int tid = threadIdx.x;
    int v = (tid < SCAN_NB) ? part[tid] : 0;
    s[tid] = v;
    __syncthreads();
#pragma unroll
    for (int off = 1; off < 256; off <<= 1) {
        int t = (tid >= off) ? s[tid - off] : 0;
        __syncthreads();
        s[tid] += t;
        __syncthreads();
    }
    if (tid < SCAN_NB) base_off[tid] = s[tid] - v;   // exclusive
    if (tid == 255) row_ptr[N_NODES] = s[255];       // total
}

__global__ void scan_apply(const int* __restrict__ cnt,
                           const int* __restrict__ base_off,
                           int* __restrict__ row_ptr,
                           int* __restrict__ cursor) {
    __shared__ int s[SCAN_B];
    int tid = threadIdx.x;
    int i = blockIdx.x * SCAN_B + tid;
    int v = (i < N_NODES) ? cnt[i] : 0;
    s[tid] = v;
    __syncthreads();
    for (int off = 1; off < SCAN_B; off <<= 1) {
        int t = (tid >= off) ? s[tid - off] : 0;
        __syncthreads();
        s[tid] += t;
        __syncthreads();
    }
    if (i < N_NODES) {
        int excl = s[tid] - v + base_off[blockIdx.x];
        row_ptr[i] = excl;
        cursor[i]  = excl;
    }
}

// ---------------------------------------------------------------------------
// Kernel: bucket scatter into CSR (sorted by col), RAW w (no dinv yet).
// ---------------------------------------------------------------------------
__global__ void csr_scatter(const int* __restrict__ edge_index,
                            const float* __restrict__ w,
                            int* __restrict__ cursor,
                            int* __restrict__ csr_src,
                            float* __restrict__ csr_w) {
    int e = blockIdx.x * blockDim.x + threadIdx.x;
    if (e >= NUM_EDGES) return;
    int r = edge_index[e];
    int c = edge_index[NUM_EDGES + e];
    int pos = atomicAdd(&cursor[c], 1);
    csr_src[pos] = r;
    csr_w[pos] = w[e];
}

// ---------------------------------------------------------------------------
// Kernel: deg[node] = coalesced segment sum of csr_w bucket; write dinv.
// One wave per node.
// ---------------------------------------------------------------------------
__global__ void deg_dinv_csr(const int* __restrict__ row_ptr,
                             const float* __restrict__ csr_w,
                             float* __restrict__ dinv) {
    int t = blockIdx.x * blockDim.x + threadIdx.x;
    int node = t >> 6;
    int lane = t & 63;
    if (node >= N_NODES) return;
    int s = row_ptr[node], e = row_ptr[node + 1];
    float sum = 0.0f;
    for (int j = s + lane; j < e; j += 64) sum += csr_w[j];
#pragma unroll
    for (int off = 32; off > 0; off >>= 1) sum += __shfl_xor(sum, off);
    if (lane == 0)
        dinv[node] = (sum > 0.0f) ? rsqrtf(fmaxf(sum, 1e-30f)) : 0.0f;
}

// ---------------------------------------------------------------------------
// Kernel: csr_w[j] *= dinv[col] * dinv[src[j]]  (wave per node, coalesced)
// ---------------------------------------------------------------------------
__global__ void csr_scale(const int* __restrict__ row_ptr,
                          const int* __restrict__ csr_src,
                          const float* __restrict__ dinv,
                          float* __restrict__ csr_w) {
    int t = blockIdx.x * blockDim.x + threadIdx.x;
    int node = t >> 6;
    int lane = t & 63;
    if (node >= N_NODES) return;
    int s = row_ptr[node], e = row_ptr[node + 1];
    float dc = dinv[node];
    for (int j = s + lane; j < e; j += 64)
        csr_w[j] = csr_w[j] * dc * dinv[csr_src[j]];
}

// ---------------------------------------------------------------------------
// Kernel: build x0 (l2norm rows), acc = x0.  One 64-lane wave per row.
// ---------------------------------------------------------------------------
__global__ void init_x(const float* __restrict__ user_w,
                       const float* __restrict__ artist_w,
                       const float* __restrict__ album_w,
                       const float* __restrict__ audio,
                       const int*   __restrict__ artist_ids,
                       const int*   __restrict__ album_ids,
                       float* __restrict__ x,
                       float* __restrict__ acc) {
    int t = blockIdx.x * blockDim.x + threadIdx.x;
    int row = t >> 6;
    int lane = t & 63;
    if (row >= N_NODES) return;

    float v;
    if (row < NUM_USERS) {
        v = user_w[row * EMBED_DIM + lane];
    } else {
        int r = row - NUM_USERS;
        int ar = artist_ids[r];
        int al = album_ids[r];
        v = audio[r * EMBED_DIM + lane]
          + 0.5f * (artist_w[ar * EMBED_DIM + lane] + album_w[al * EMBED_DIM + lane]);
    }
    float ss = v * v;
#pragma unroll
    for (int off = 32; off > 0; off >>= 1) ss += __shfl_xor(ss, off);
    float scale = 1.0f / fmaxf(sqrtf(ss), 1e-12f);
    float o = v * scale;
    x[row * EMBED_DIM + lane] = o;
    acc[row * EMBED_DIM + lane] = o;
}

// ---------------------------------------------------------------------------
// Kernel: pull-mode propagation. One wave per node; lane = embed dim.
// ---------------------------------------------------------------------------
template <bool FINAL>
__global__ void propagate_pull(const int* __restrict__ row_ptr,
                               const int* __restrict__ csr_src,
                               const float* __restrict__ csr_w,
                               const float* __restrict__ xin,
                               float* __restrict__ xout,
                               float* __restrict__ acc) {
    int t = blockIdx.x * blockDim.x + threadIdx.x;
    int node = t >> 6;
    int lane = t & 63;
    if (node >= N_NODES) return;

    int start = row_ptr[node];
    int end   = row_ptr[node + 1];

    float a = 0.0f;
    for (int base = start; base < end; base += 64) {
        int j = base + lane;
        int src = 0;
        float nw = 0.0f;
        if (j < end) { src = csr_src[j]; nw = csr_w[j]; }
        int cnt = end - base; if (cnt > 64) cnt = 64;
        for (int tt = 0; tt < cnt; ++tt) {
            int s = __shfl(src, tt);
            float n = __shfl(nw, tt);
            a = fmaf(n, xin[(size_t)s * EMBED_DIM + lane], a);
        }
    }

    size_t o = (size_t)node * EMBED_DIM + lane;
    if (FINAL) {
        float v = (acc[o] + a) * 0.25f;
        float ss = v * v;
#pragma unroll
        for (int off = 32; off > 0; off >>= 1) ss += __shfl_xor(ss, off);
        float scale = 1.0f / fmaxf(sqrtf(ss), 1e-12f);
        acc[o] = v * scale;
        if (blockIdx.x == 0 && threadIdx.x == 0)
            acc[(size_t)N_NODES * EMBED_DIM] = 0.0f;  // align_loss
    } else {
        xout[o] = a;
        acc[o] = acc[o] + a;
    }
}

// ---------------------------------------------------------------------------
extern "C" void kernel_launch(void* const* d_in, const int* in_sizes, int n_in,
                              void* d_out, int out_size, void* d_ws, size_t ws_size,
                              hipStream_t stream) {
    const float* user_w     = (const float*)d_in[0];
    const float* artist_w   = (const float*)d_in[1];
    const float* album_w    = (const float*)d_in[2];
    const float* audio      = (const float*)d_in[3];
    const float* edge_attr  = (const float*)d_in[4];
    const float* ew         = (const float*)d_in[5];
    const float* w1         = (const float*)d_in[6];
    const float* b1         = (const float*)d_in[7];
    const float* w2         = (const float*)d_in[8];
    const float* b2         = (const float*)d_in[9];
    const int*   edge_index = (const int*)d_in[10];
    const int*   artist_ids = (const int*)d_in[11];
    const int*   album_ids  = (const int*)d_in[12];
    float* out = (float*)d_out;

    float* ws = (float*)d_ws;
    // Persistent regions (footprint identical to the proven 87.44 MB layout):
    float* xa      = ws;                        // 9.6M floats
    float* xb      = ws + 9600000;              // 9.6M floats
    int*   row_ptr = (int*)(ws + 19200000);     // 150001 ints
    int*   csr_src = (int*)(ws + 19360000);     // 1.25M ints
    float* csr_w   = ws + 20610000;             // 1.25M floats
    // Transients aliased into xa (all dead before init_x writes xa):
    float* wraw    = ws;                        // 1.25M floats (MLP sigmoid out)
    int*   cnt     = (int*)(ws + 1250000);      // 150k ints
    int*   cursor  = (int*)(ws + 1400000);      // 150k ints
    int*   part    = (int*)(ws + 1550000);      // 147 ints
    int*   baseoff = (int*)(ws + 1551000);      // 147 ints
    float* dinv    = ws + 1552000;              // 150k floats (dead before init_x)

    const int B = 256;

    hipMemsetAsync(cnt, 0, N_NODES * sizeof(int), stream);

    edge_mlp_hist<<<(NUM_EDGES + B - 1) / B, B, 0, stream>>>(
        edge_attr, ew, w1, b1, w2, b2, edge_index, wraw, cnt);

    scan_partial<<<SCAN_NB, SCAN_B, 0, stream>>>(cnt, part);
    scan_offsets<<<1, 256, 0, stream>>>(part, baseoff, row_ptr);
    scan_apply<<<SCAN_NB, SCAN_B, 0, stream>>>(cnt, baseoff, row_ptr, cursor);

    csr_scatter<<<(NUM_EDGES + B - 1) / B, B, 0, stream>>>(
        edge_index, wraw, cursor, csr_src, csr_w);

    const int ngrid = (N_NODES * EMBED_DIM) / B;  // wave-per-node grids
    deg_dinv_csr<<<ngrid, B, 0, stream>>>(row_ptr, csr_w, dinv);
    csr_scale<<<ngrid, B, 0, stream>>>(row_ptr, csr_src, dinv, csr_w);

    init_x<<<ngrid, B, 0, stream>>>(
        user_w, artist_w, album_w, audio, artist_ids, album_ids, xa, out);

    propagate_pull<false><<<ngrid, B, 0, stream>>>(row_ptr, csr_src, csr_w, xa, xb, out);
    propagate_pull<false><<<ngrid, B, 0, stream>>>(row_ptr, csr_src, csr_w, xb, xa, out);
    propagate_pull<true ><<<ngrid, B, 0, stream>>>(row_ptr, csr_src, csr_w, xa, xb, out);
}

// Round 5
// 605.303 us; speedup vs baseline: 1.9099x; 1.0698x over previous
//
#include <hip/hip_runtime.h>
#include <hip/hip_bf16.h>
#include <math.h>

#define NUM_USERS  100000
#define NUM_ITEMS  50000
#define N_NODES    150000
#define EMBED_DIM  64
#define NUM_EDGES  1250000
#define MLP_HID    32
#define SCAN_B     1024
#define SCAN_NB    ((N_NODES + SCAN_B - 1) / SCAN_B)   // 147

// ---------------------------------------------------------------------------
// Kernel 1: histogram of cols + within-bucket rank (the atomic's return value
// IS the rank -> downstream scatter needs no atomics).
// ---------------------------------------------------------------------------
__global__ void hist_rank(const int* __restrict__ edge_index,
                          int* __restrict__ cnt,
                          int* __restrict__ rank) {
    int e = blockIdx.x * blockDim.x + threadIdx.x;
    if (e >= NUM_EDGES) return;
    int c = edge_index[NUM_EDGES + e];
    rank[e] = atomicAdd(&cnt[c], 1);
}

// ---------------------------------------------------------------------------
// Device-wide exclusive scan of cnt -> row_ptr, 3 phases.
// ---------------------------------------------------------------------------
__global__ void scan_partial(const int* __restrict__ cnt,
                             int* __restrict__ part) {
    __shared__ int s[SCAN_B];
    int tid = threadIdx.x;
    int i = blockIdx.x * SCAN_B + tid;
    s[tid] = (i < N_NODES) ? cnt[i] : 0;
    __syncthreads();
#pragma unroll
    for (int off = SCAN_B / 2; off > 0; off >>= 1) {
        if (tid < off) s[tid] += s[tid + off];
        __syncthreads();
    }
    if (tid == 0) part[blockIdx.x] = s[0];
}

__global__ void scan_offsets(const int* __restrict__ part,
                             int* __restrict__ base_off,
                             int* __restrict__ row_ptr) {
    __shared__ int s[256];
    int tid = threadIdx.x;
    int v = (tid < SCAN_NB) ? part[tid] : 0;
    s[tid] = v;
    __syncthreads();
#pragma unroll
    for (int off = 1; off < 256; off <<= 1) {
        int t = (tid >= off) ? s[tid - off] : 0;
        __syncthreads();
        s[tid] += t;
        __syncthreads();
    }
    if (tid < SCAN_NB) base_off[tid] = s[tid] - v;   // exclusive
    if (tid == 255) row_ptr[N_NODES] = s[255];       // total
}

__global__ void scan_apply(const int* __restrict__ cnt,
                           const int* __restrict__ base_off,
                           int* __restrict__ row_ptr) {
    __shared__ int s[SCAN_B];
    int tid = threadIdx.x;
    int i = blockIdx.x * SCAN_B + tid;
    int v = (i < N_NODES) ? cnt[i] : 0;
    s[tid] = v;
    __syncthreads();
    for (int off = 1; off < SCAN_B; off <<= 1) {
        int t = (tid >= off) ? s[tid - off] : 0;
        __syncthreads();
        s[tid] += t;
        __syncthreads();
    }
    if (i < N_NODES) row_ptr[i] = s[tid] - v + base_off[blockIdx.x];
}

// ---------------------------------------------------------------------------
// Kernel 2: per-edge MLP fused with ATOMIC-FREE CSR scatter:
// pos = row_ptr[col] + rank[e]  (rank from the histogram pass).
// ---------------------------------------------------------------------------
__global__ void mlp_scatter(const float* __restrict__ edge_attr,
                            const float* __restrict__ ew,
                            const float* __restrict__ w1,
                            const float* __restrict__ b1,
                            const float* __restrict__ w2,
                            const float* __restrict__ b2,
                            const int*   __restrict__ edge_index,
                            const int*   __restrict__ rank,
                            const int*   __restrict__ row_ptr,
                            int*   __restrict__ csr_src,
                            float* __restrict__ csr_w) {
    __shared__ float w1s[8 * MLP_HID];
    __shared__ float b1s[MLP_HID];
    __shared__ float w2s[MLP_HID];
    int tid = threadIdx.x;
    if (tid < 8 * MLP_HID) w1s[tid] = w1[tid];
    if (tid < MLP_HID) { b1s[tid] = b1[tid]; w2s[tid] = w2[tid]; }
    __syncthreads();

    int e = blockIdx.x * blockDim.x + tid;
    if (e >= NUM_EDGES) return;

    float ef[8];
#pragma unroll
    for (int k = 0; k < 7; ++k) ef[k] = edge_attr[e * 7 + k];
    ef[7] = ew[e];

    float s = b2[0];
#pragma unroll
    for (int j = 0; j < MLP_HID; ++j) {
        float h = b1s[j];
#pragma unroll
        for (int k = 0; k < 8; ++k) h = fmaf(ef[k], w1s[k * MLP_HID + j], h);
        h = fmaxf(h, 0.0f);
        s = fmaf(h, w2s[j], s);
    }
    float w = 1.0f / (1.0f + expf(-s));

    int r = edge_index[e];
    int c = edge_index[NUM_EDGES + e];
    int pos = row_ptr[c] + rank[e];
    csr_src[pos] = r;
    csr_w[pos] = w;
}

// ---------------------------------------------------------------------------
// deg[node] = coalesced segment sum of csr_w bucket; write dinv.
// ---------------------------------------------------------------------------
__global__ void deg_dinv_csr(const int* __restrict__ row_ptr,
                             const float* __restrict__ csr_w,
                             float* __restrict__ dinv) {
    int t = blockIdx.x * blockDim.x + threadIdx.x;
    int node = t >> 6;
    int lane = t & 63;
    if (node >= N_NODES) return;
    int s = row_ptr[node], e = row_ptr[node + 1];
    float sum = 0.0f;
    for (int j = s + lane; j < e; j += 64) sum += csr_w[j];
#pragma unroll
    for (int off = 32; off > 0; off >>= 1) sum += __shfl_xor(sum, off);
    if (lane == 0)
        dinv[node] = (sum > 0.0f) ? rsqrtf(fmaxf(sum, 1e-30f)) : 0.0f;
}

// ---------------------------------------------------------------------------
// csr_w[j] *= dinv[col] * dinv[src[j]]
// ---------------------------------------------------------------------------
__global__ void csr_scale(const int* __restrict__ row_ptr,
                          const int* __restrict__ csr_src,
                          const float* __restrict__ dinv,
                          float* __restrict__ csr_w) {
    int t = blockIdx.x * blockDim.x + threadIdx.x;
    int node = t >> 6;
    int lane = t & 63;
    if (node >= N_NODES) return;
    int s = row_ptr[node], e = row_ptr[node + 1];
    float dc = dinv[node];
    for (int j = s + lane; j < e; j += 64)
        csr_w[j] = csr_w[j] * dc * dinv[csr_src[j]];
}

// ---------------------------------------------------------------------------
// build x0: bf16 x table (halves gather bytes), f32 acc (= d_out).
// ---------------------------------------------------------------------------
__global__ void init_x(const float* __restrict__ user_w,
                       const float* __restrict__ artist_w,
                       const float* __restrict__ album_w,
                       const float* __restrict__ audio,
                       const int*   __restrict__ artist_ids,
                       const int*   __restrict__ album_ids,
                       __hip_bfloat16* __restrict__ x,
                       float* __restrict__ acc) {
    int t = blockIdx.x * blockDim.x + threadIdx.x;
    int row = t >> 6;
    int lane = t & 63;
    if (row >= N_NODES) return;

    float v;
    if (row < NUM_USERS) {
        v = user_w[row * EMBED_DIM + lane];
    } else {
        int r = row - NUM_USERS;
        int ar = artist_ids[r];
        int al = album_ids[r];
        v = audio[r * EMBED_DIM + lane]
          + 0.5f * (artist_w[ar * EMBED_DIM + lane] + album_w[al * EMBED_DIM + lane]);
    }
    float ss = v * v;
#pragma unroll
    for (int off = 32; off > 0; off >>= 1) ss += __shfl_xor(ss, off);
    float scale = 1.0f / fmaxf(sqrtf(ss), 1e-12f);
    float o = v * scale;
    x[row * EMBED_DIM + lane] = __float2bfloat16(o);
    acc[row * EMBED_DIM + lane] = o;
}

// ---------------------------------------------------------------------------
// pull-mode propagation, bf16 gathers, f32 accumulate.
// ---------------------------------------------------------------------------
template <bool FINAL>
__global__ void propagate_pull(const int* __restrict__ row_ptr,
                               const int* __restrict__ csr_src,
                               const float* __restrict__ csr_w,
                               const __hip_bfloat16* __restrict__ xin,
                               __hip_bfloat16* __restrict__ xout,
                               float* __restrict__ acc) {
    int t = blockIdx.x * blockDim.x + threadIdx.x;
    int node = t >> 6;
    int lane = t & 63;
    if (node >= N_NODES) return;

    int start = row_ptr[node];
    int end   = row_ptr[node + 1];

    float a = 0.0f;
    for (int base = start; base < end; base += 64) {
        int j = base + lane;
        int src = 0;
        float nw = 0.0f;
        if (j < end) { src = csr_src[j]; nw = csr_w[j]; }
        int cnt = end - base; if (cnt > 64) cnt = 64;
        for (int tt = 0; tt < cnt; ++tt) {
            int s = __shfl(src, tt);
            float n = __shfl(nw, tt);
            float xv = __bfloat162float(xin[(size_t)s * EMBED_DIM + lane]);
            a = fmaf(n, xv, a);
        }
    }

    size_t o = (size_t)node * EMBED_DIM + lane;
    if (FINAL) {
        float v = (acc[o] + a) * 0.25f;
        float ss = v * v;
#pragma unroll
        for (int off = 32; off > 0; off >>= 1) ss += __shfl_xor(ss, off);
        float scale = 1.0f / fmaxf(sqrtf(ss), 1e-12f);
        acc[o] = v * scale;
        if (blockIdx.x == 0 && threadIdx.x == 0)
            acc[(size_t)N_NODES * EMBED_DIM] = 0.0f;  // align_loss
    } else {
        xout[o] = __float2bfloat16(a);
        acc[o] = acc[o] + a;
    }
}

// ---------------------------------------------------------------------------
extern "C" void kernel_launch(void* const* d_in, const int* in_sizes, int n_in,
                              void* d_out, int out_size, void* d_ws, size_t ws_size,
                              hipStream_t stream) {
    const float* user_w     = (const float*)d_in[0];
    const float* artist_w   = (const float*)d_in[1];
    const float* album_w    = (const float*)d_in[2];
    const float* audio      = (const float*)d_in[3];
    const float* edge_attr  = (const float*)d_in[4];
    const float* ew         = (const float*)d_in[5];
    const float* w1         = (const float*)d_in[6];
    const float* b1         = (const float*)d_in[7];
    const float* w2         = (const float*)d_in[8];
    const float* b2         = (const float*)d_in[9];
    const int*   edge_index = (const int*)d_in[10];
    const int*   artist_ids = (const int*)d_in[11];
    const int*   album_ids  = (const int*)d_in[12];
    float* out = (float*)d_out;

    float* ws = (float*)d_ws;
    // Persistent regions (offsets in float units):
    __hip_bfloat16* xa = (__hip_bfloat16*)ws;               // 9.6M bf16 = 4.8M floats
    __hip_bfloat16* xb = (__hip_bfloat16*)(ws + 4800000);   // 9.6M bf16
    int*   row_ptr = (int*)(ws + 9600000);                  // 150001 ints
    int*   csr_src = (int*)(ws + 9760000);                  // 1.25M ints
    float* csr_w   = ws + 11010000;                         // 1.25M floats
    float* dinv    = ws + 12260000;                         // 150k floats
    // Transients aliased into xa's region (all dead before init_x writes xa):
    int*   cnt     = (int*)ws;                              // 150k ints
    int*   rank    = (int*)(ws + 150000);                   // 1.25M ints
    int*   part    = (int*)(ws + 1400000);                  // 147 ints
    int*   baseoff = (int*)(ws + 1401000);                  // 147 ints

    const int B = 256;
    const int egrid = (NUM_EDGES + B - 1) / B;
    const int ngrid = (N_NODES * EMBED_DIM) / B;  // wave-per-node grids

    hipMemsetAsync(cnt, 0, N_NODES * sizeof(int), stream);

    hist_rank<<<egrid, B, 0, stream>>>(edge_index, cnt, rank);

    scan_partial<<<SCAN_NB, SCAN_B, 0, stream>>>(cnt, part);
    scan_offsets<<<1, 256, 0, stream>>>(part, baseoff, row_ptr);
    scan_apply<<<SCAN_NB, SCAN_B, 0, stream>>>(cnt, baseoff, row_ptr);

    mlp_scatter<<<egrid, B, 0, stream>>>(
        edge_attr, ew, w1, b1, w2, b2, edge_index, rank, row_ptr, csr_src, csr_w);

    deg_dinv_csr<<<ngrid, B, 0, stream>>>(row_ptr, csr_w, dinv);
    csr_scale<<<ngrid, B, 0, stream>>>(row_ptr, csr_src, dinv, csr_w);

    init_x<<<ngrid, B, 0, stream>>>(
        user_w, artist_w, album_w, audio, artist_ids, album_ids, xa, out);

    propagate_pull<false><<<ngrid, B, 0, stream>>>(row_ptr, csr_src, csr_w, xa, xb, out);
    propagate_pull<false><<<ngrid, B, 0, stream>>>(row_ptr, csr_src, csr_w, xb, xa, out);
    propagate_pull<true ><<<ngrid, B, 0, stream>>>(row_ptr, csr_src, csr_w, xa, xb, out);
}

// Round 6
// 495.535 us; speedup vs baseline: 2.3329x; 1.2215x over previous
//
#include <hip/hip_runtime.h>
#include <hip/hip_bf16.h>
#include <math.h>

#define NUM_USERS  100000
#define NUM_ITEMS  50000
#define N_NODES    150000
#define EMBED_DIM  64
#define NUM_EDGES  1250000
#define MLP_HID    32
#define SCAN_B     1024
#define SCAN_NB    ((N_NODES + SCAN_B - 1) / SCAN_B)   // 147

// ---------------------------------------------------------------------------
// Kernel 1: histogram of cols + within-bucket rank (atomic return value IS
// the rank -> downstream scatter needs no atomics).
// ---------------------------------------------------------------------------
__global__ void hist_rank(const int* __restrict__ edge_index,
                          int* __restrict__ cnt,
                          int* __restrict__ rank) {
    int e = blockIdx.x * blockDim.x + threadIdx.x;
    if (e >= NUM_EDGES) return;
    int c = edge_index[NUM_EDGES + e];
    rank[e] = atomicAdd(&cnt[c], 1);
}

// ---------------------------------------------------------------------------
// Device-wide exclusive scan of cnt -> row_ptr, 3 phases.
// ---------------------------------------------------------------------------
__global__ void scan_partial(const int* __restrict__ cnt,
                             int* __restrict__ part) {
    __shared__ int s[SCAN_B];
    int tid = threadIdx.x;
    int i = blockIdx.x * SCAN_B + tid;
    s[tid] = (i < N_NODES) ? cnt[i] : 0;
    __syncthreads();
#pragma unroll
    for (int off = SCAN_B / 2; off > 0; off >>= 1) {
        if (tid < off) s[tid] += s[tid + off];
        __syncthreads();
    }
    if (tid == 0) part[blockIdx.x] = s[0];
}

__global__ void scan_offsets(const int* __restrict__ part,
                             int* __restrict__ base_off,
                             int* __restrict__ row_ptr) {
    __shared__ int s[256];
    int tid = threadIdx.x;
    int v = (tid < SCAN_NB) ? part[tid] : 0;
    s[tid] = v;
    __syncthreads();
#pragma unroll
    for (int off = 1; off < 256; off <<= 1) {
        int t = (tid >= off) ? s[tid - off] : 0;
        __syncthreads();
        s[tid] += t;
        __syncthreads();
    }
    if (tid < SCAN_NB) base_off[tid] = s[tid] - v;   // exclusive
    if (tid == 255) row_ptr[N_NODES] = s[255];       // total
}

__global__ void scan_apply(const int* __restrict__ cnt,
                           const int* __restrict__ base_off,
                           int* __restrict__ row_ptr) {
    __shared__ int s[SCAN_B];
    int tid = threadIdx.x;
    int i = blockIdx.x * SCAN_B + tid;
    int v = (i < N_NODES) ? cnt[i] : 0;
    s[tid] = v;
    __syncthreads();
    for (int off = 1; off < SCAN_B; off <<= 1) {
        int t = (tid >= off) ? s[tid - off] : 0;
        __syncthreads();
        s[tid] += t;
        __syncthreads();
    }
    if (i < N_NODES) row_ptr[i] = s[tid] - v + base_off[blockIdx.x];
}

// ---------------------------------------------------------------------------
// Kernel 2: per-edge MLP fused with ATOMIC-FREE CSR scatter.
// ---------------------------------------------------------------------------
__global__ void mlp_scatter(const float* __restrict__ edge_attr,
                            const float* __restrict__ ew,
                            const float* __restrict__ w1,
                            const float* __restrict__ b1,
                            const float* __restrict__ w2,
                            const float* __restrict__ b2,
                            const int*   __restrict__ edge_index,
                            const int*   __restrict__ rank,
                            const int*   __restrict__ row_ptr,
                            int*   __restrict__ csr_src,
                            float* __restrict__ csr_w) {
    __shared__ float w1s[8 * MLP_HID];
    __shared__ float b1s[MLP_HID];
    __shared__ float w2s[MLP_HID];
    int tid = threadIdx.x;
    if (tid < 8 * MLP_HID) w1s[tid] = w1[tid];
    if (tid < MLP_HID) { b1s[tid] = b1[tid]; w2s[tid] = w2[tid]; }
    __syncthreads();

    int e = blockIdx.x * blockDim.x + tid;
    if (e >= NUM_EDGES) return;

    float ef[8];
#pragma unroll
    for (int k = 0; k < 7; ++k) ef[k] = edge_attr[e * 7 + k];
    ef[7] = ew[e];

    float s = b2[0];
#pragma unroll
    for (int j = 0; j < MLP_HID; ++j) {
        float h = b1s[j];
#pragma unroll
        for (int k = 0; k < 8; ++k) h = fmaf(ef[k], w1s[k * MLP_HID + j], h);
        h = fmaxf(h, 0.0f);
        s = fmaf(h, w2s[j], s);
    }
    float w = 1.0f / (1.0f + expf(-s));

    int r = edge_index[e];
    int c = edge_index[NUM_EDGES + e];
    int pos = row_ptr[c] + rank[e];
    csr_src[pos] = r;
    csr_w[pos] = w;
}

// ---------------------------------------------------------------------------
// deg[node] = coalesced segment sum of csr_w bucket; write dinv.
// ---------------------------------------------------------------------------
__global__ void deg_dinv_csr(const int* __restrict__ row_ptr,
                             const float* __restrict__ csr_w,
                             float* __restrict__ dinv) {
    int t = blockIdx.x * blockDim.x + threadIdx.x;
    int node = t >> 6;
    int lane = t & 63;
    if (node >= N_NODES) return;
    int s = row_ptr[node], e = row_ptr[node + 1];
    float sum = 0.0f;
    for (int j = s + lane; j < e; j += 64) sum += csr_w[j];
#pragma unroll
    for (int off = 32; off > 0; off >>= 1) sum += __shfl_xor(sum, off);
    if (lane == 0)
        dinv[node] = (sum > 0.0f) ? rsqrtf(fmaxf(sum, 1e-30f)) : 0.0f;
}

// ---------------------------------------------------------------------------
// csr_w[j] *= dinv[col] * dinv[src[j]]
// ---------------------------------------------------------------------------
__global__ void csr_scale(const int* __restrict__ row_ptr,
                          const int* __restrict__ csr_src,
                          const float* __restrict__ dinv,
                          float* __restrict__ csr_w) {
    int t = blockIdx.x * blockDim.x + threadIdx.x;
    int node = t >> 6;
    int lane = t & 63;
    if (node >= N_NODES) return;
    int s = row_ptr[node], e = row_ptr[node + 1];
    float dc = dinv[node];
    for (int j = s + lane; j < e; j += 64)
        csr_w[j] = csr_w[j] * dc * dinv[csr_src[j]];
}

// ---------------------------------------------------------------------------
// build x0: bf16 x table, f32 acc (= d_out).
// ---------------------------------------------------------------------------
__global__ void init_x(const float* __restrict__ user_w,
                       const float* __restrict__ artist_w,
                       const float* __restrict__ album_w,
                       const float* __restrict__ audio,
                       const int*   __restrict__ artist_ids,
                       const int*   __restrict__ album_ids,
                       __hip_bfloat16* __restrict__ x,
                       float* __restrict__ acc) {
    int t = blockIdx.x * blockDim.x + threadIdx.x;
    int row = t >> 6;
    int lane = t & 63;
    if (row >= N_NODES) return;

    float v;
    if (row < NUM_USERS) {
        v = user_w[row * EMBED_DIM + lane];
    } else {
        int r = row - NUM_USERS;
        int ar = artist_ids[r];
        int al = album_ids[r];
        v = audio[r * EMBED_DIM + lane]
          + 0.5f * (artist_w[ar * EMBED_DIM + lane] + album_w[al * EMBED_DIM + lane]);
    }
    float ss = v * v;
#pragma unroll
    for (int off = 32; off > 0; off >>= 1) ss += __shfl_xor(ss, off);
    float scale = 1.0f / fmaxf(sqrtf(ss), 1e-12f);
    float o = v * scale;
    x[row * EMBED_DIM + lane] = __float2bfloat16(o);
    acc[row * EMBED_DIM + lane] = o;
}

// ---------------------------------------------------------------------------
// pull-mode propagation, 8 edges x 8 dims per lane.
// Lane L: edge slot eg=L>>3, dim octet dq=8*(L&7). Per iteration: one uint4
// (8 bf16) gather + 8 FMAs covers 8 edges/wave. Private a[8] accumulators;
// shfl_xor(8/16/32) epilogue folds edge slots. No in-loop cross-lane ops.
// ---------------------------------------------------------------------------
template <bool FINAL>
__global__ void propagate_pull(const int* __restrict__ row_ptr,
                               const int* __restrict__ csr_src,
                               const float* __restrict__ csr_w,
                               const unsigned short* __restrict__ xin,
                               unsigned short* __restrict__ xout,
                               float* __restrict__ acc) {
    int t = blockIdx.x * blockDim.x + threadIdx.x;
    int node = t >> 6;
    int lane = t & 63;
    if (node >= N_NODES) return;

    int start = row_ptr[node];
    int end   = row_ptr[node + 1];

    int eg = lane >> 3;          // edge slot 0..7
    int dq = (lane & 7) << 3;    // dim octet start

    float a0 = 0, a1 = 0, a2 = 0, a3 = 0, a4 = 0, a5 = 0, a6 = 0, a7 = 0;

    for (int base = start; base < end; base += 8) {
        int j = base + eg;
        int src = 0; float nw = 0.0f;
        if (j < end) { src = csr_src[j]; nw = csr_w[j]; }
        const uint4* p = (const uint4*)(xin + ((size_t)src << 6) + dq);
        uint4 u = *p;
        a0 = fmaf(nw, __uint_as_float(u.x << 16),          a0);
        a1 = fmaf(nw, __uint_as_float(u.x & 0xffff0000u),  a1);
        a2 = fmaf(nw, __uint_as_float(u.y << 16),          a2);
        a3 = fmaf(nw, __uint_as_float(u.y & 0xffff0000u),  a3);
        a4 = fmaf(nw, __uint_as_float(u.z << 16),          a4);
        a5 = fmaf(nw, __uint_as_float(u.z & 0xffff0000u),  a5);
        a6 = fmaf(nw, __uint_as_float(u.w << 16),          a6);
        a7 = fmaf(nw, __uint_as_float(u.w & 0xffff0000u),  a7);
    }

    // fold the 8 edge slots (lanes differing in bits 3..5)
#pragma unroll
    for (int off = 8; off <= 32; off <<= 1) {
        a0 += __shfl_xor(a0, off); a1 += __shfl_xor(a1, off);
        a2 += __shfl_xor(a2, off); a3 += __shfl_xor(a3, off);
        a4 += __shfl_xor(a4, off); a5 += __shfl_xor(a5, off);
        a6 += __shfl_xor(a6, off); a7 += __shfl_xor(a7, off);
    }
    // now all lanes with the same (lane&7) hold dims [dq, dq+8) totals

    size_t o = ((size_t)node << 6) + dq;
    if (FINAL) {
        // all lanes load acc (8-way broadcast, L1-served) to compute ss
        const float4* ap = (const float4*)(acc + o);
        float4 c0 = ap[0], c1 = ap[1];
        float v0 = (c0.x + a0) * 0.25f, v1 = (c0.y + a1) * 0.25f;
        float v2 = (c0.z + a2) * 0.25f, v3 = (c0.w + a3) * 0.25f;
        float v4 = (c1.x + a4) * 0.25f, v5 = (c1.y + a5) * 0.25f;
        float v6 = (c1.z + a6) * 0.25f, v7 = (c1.w + a7) * 0.25f;
        float ss = v0*v0 + v1*v1 + v2*v2 + v3*v3 + v4*v4 + v5*v5 + v6*v6 + v7*v7;
#pragma unroll
        for (int off = 1; off <= 4; off <<= 1) ss += __shfl_xor(ss, off);
        float scale = 1.0f / fmaxf(sqrtf(ss), 1e-12f);
        if (eg == 0) {
            float4 r0 = { v0*scale, v1*scale, v2*scale, v3*scale };
            float4 r1 = { v4*scale, v5*scale, v6*scale, v7*scale };
            float4* wp = (float4*)(acc + o);
            wp[0] = r0; wp[1] = r1;
        }
        if (blockIdx.x == 0 && threadIdx.x == 0)
            acc[(size_t)N_NODES * EMBED_DIM] = 0.0f;  // align_loss
    } else {
        if (eg == 0) {
            // acc += a  (read-modify-write, 2x float4)
            float4* ap = (float4*)(acc + o);
            float4 c0 = ap[0], c1 = ap[1];
            c0.x += a0; c0.y += a1; c0.z += a2; c0.w += a3;
            c1.x += a4; c1.y += a5; c1.z += a6; c1.w += a7;
            ap[0] = c0; ap[1] = c1;
            // xout = bf16(a), packed 8 -> one uint4 store
            unsigned int b0 = (unsigned int)__bfloat16_as_ushort(__float2bfloat16(a0));
            unsigned int b1 = (unsigned int)__bfloat16_as_ushort(__float2bfloat16(a1));
            unsigned int b2 = (unsigned int)__bfloat16_as_ushort(__float2bfloat16(a2));
            unsigned int b3 = (unsigned int)__bfloat16_as_ushort(__float2bfloat16(a3));
            unsigned int b4 = (unsigned int)__bfloat16_as_ushort(__float2bfloat16(a4));
            unsigned int b5 = (unsigned int)__bfloat16_as_ushort(__float2bfloat16(a5));
            unsigned int b6 = (unsigned int)__bfloat16_as_ushort(__float2bfloat16(a6));
            unsigned int b7 = (unsigned int)__bfloat16_as_ushort(__float2bfloat16(a7));
            uint4 u;
            u.x = b0 | (b1 << 16); u.y = b2 | (b3 << 16);
            u.z = b4 | (b5 << 16); u.w = b6 | (b7 << 16);
            *(uint4*)(xout + o) = u;
        }
    }
}

// ---------------------------------------------------------------------------
extern "C" void kernel_launch(void* const* d_in, const int* in_sizes, int n_in,
                              void* d_out, int out_size, void* d_ws, size_t ws_size,
                              hipStream_t stream) {
    const float* user_w     = (const float*)d_in[0];
    const float* artist_w   = (const float*)d_in[1];
    const float* album_w    = (const float*)d_in[2];
    const float* audio      = (const float*)d_in[3];
    const float* edge_attr  = (const float*)d_in[4];
    const float* ew         = (const float*)d_in[5];
    const float* w1         = (const float*)d_in[6];
    const float* b1         = (const float*)d_in[7];
    const float* w2         = (const float*)d_in[8];
    const float* b2         = (const float*)d_in[9];
    const int*   edge_index = (const int*)d_in[10];
    const int*   artist_ids = (const int*)d_in[11];
    const int*   album_ids  = (const int*)d_in[12];
    float* out = (float*)d_out;

    float* ws = (float*)d_ws;
    // Persistent regions (offsets in float units):
    unsigned short* xa = (unsigned short*)ws;               // 9.6M bf16
    unsigned short* xb = (unsigned short*)(ws + 4800000);   // 9.6M bf16
    int*   row_ptr = (int*)(ws + 9600000);                  // 150001 ints
    int*   csr_src = (int*)(ws + 9760000);                  // 1.25M ints
    float* csr_w   = ws + 11010000;                         // 1.25M floats
    float* dinv    = ws + 12260000;                         // 150k floats
    // Transients aliased into xa's region (dead before init_x writes xa):
    int*   cnt     = (int*)ws;                              // 150k ints
    int*   rank    = (int*)(ws + 150000);                   // 1.25M ints
    int*   part    = (int*)(ws + 1400000);                  // 147 ints
    int*   baseoff = (int*)(ws + 1401000);                  // 147 ints

    const int B = 256;
    const int egrid = (NUM_EDGES + B - 1) / B;
    const int ngrid = (N_NODES * EMBED_DIM) / B;  // wave-per-node grids

    hipMemsetAsync(cnt, 0, N_NODES * sizeof(int), stream);

    hist_rank<<<egrid, B, 0, stream>>>(edge_index, cnt, rank);

    scan_partial<<<SCAN_NB, SCAN_B, 0, stream>>>(cnt, part);
    scan_offsets<<<1, 256, 0, stream>>>(part, baseoff, row_ptr);
    scan_apply<<<SCAN_NB, SCAN_B, 0, stream>>>(cnt, baseoff, row_ptr);

    mlp_scatter<<<egrid, B, 0, stream>>>(
        edge_attr, ew, w1, b1, w2, b2, edge_index, rank, row_ptr, csr_src, csr_w);

    deg_dinv_csr<<<ngrid, B, 0, stream>>>(row_ptr, csr_w, dinv);
    csr_scale<<<ngrid, B, 0, stream>>>(row_ptr, csr_src, dinv, csr_w);

    init_x<<<ngrid, B, 0, stream>>>(
        user_w, artist_w, album_w, audio, artist_ids, album_ids,
        (__hip_bfloat16*)xa, out);

    propagate_pull<false><<<ngrid, B, 0, stream>>>(row_ptr, csr_src, csr_w, xa, xb, out);
    propagate_pull<false><<<ngrid, B, 0, stream>>>(row_ptr, csr_src, csr_w, xb, xa, out);
    propagate_pull<true ><<<ngrid, B, 0, stream>>>(row_ptr, csr_src, csr_w, xa, xb, out);
}

// Round 7
// 462.608 us; speedup vs baseline: 2.4990x; 1.0712x over previous
//
#include <hip/hip_runtime.h>
#include <hip/hip_bf16.h>
#include <math.h>

#define NUM_USERS  100000
#define NUM_ITEMS  50000
#define N_NODES    150000
#define EMBED_DIM  64
#define NUM_EDGES  1250000
#define MLP_HID    32
#define SCAN_B     1024
#define SCAN_NB    ((N_NODES + SCAN_B - 1) / SCAN_B)   // 147

// ---------------------------------------------------------------------------
// Kernel 1: histogram of cols + within-bucket rank (atomic return value IS
// the rank -> downstream scatter needs no atomics).
// ---------------------------------------------------------------------------
__global__ void hist_rank(const int* __restrict__ edge_index,
                          int* __restrict__ cnt,
                          int* __restrict__ rank) {
    int e = blockIdx.x * blockDim.x + threadIdx.x;
    if (e >= NUM_EDGES) return;
    int c = edge_index[NUM_EDGES + e];
    rank[e] = atomicAdd(&cnt[c], 1);
}

// ---------------------------------------------------------------------------
// Device-wide exclusive scan of cnt -> row_ptr, 3 phases.
// ---------------------------------------------------------------------------
__global__ void scan_partial(const int* __restrict__ cnt,
                             int* __restrict__ part) {
    __shared__ int s[SCAN_B];
    int tid = threadIdx.x;
    int i = blockIdx.x * SCAN_B + tid;
    s[tid] = (i < N_NODES) ? cnt[i] : 0;
    __syncthreads();
#pragma unroll
    for (int off = SCAN_B / 2; off > 0; off >>= 1) {
        if (tid < off) s[tid] += s[tid + off];
        __syncthreads();
    }
    if (tid == 0) part[blockIdx.x] = s[0];
}

__global__ void scan_offsets(const int* __restrict__ part,
                             int* __restrict__ base_off) {
    __shared__ int s[256];
    int tid = threadIdx.x;
    int v = (tid < SCAN_NB) ? part[tid] : 0;
    s[tid] = v;
    __syncthreads();
#pragma unroll
    for (int off = 1; off < 256; off <<= 1) {
        int t = (tid >= off) ? s[tid - off] : 0;
        __syncthreads();
        s[tid] += t;
        __syncthreads();
    }
    if (tid < SCAN_NB) base_off[tid] = s[tid] - v;   // exclusive
}

__global__ void scan_apply(const int* __restrict__ cnt,
                           const int* __restrict__ base_off,
                           int* __restrict__ row_ptr) {
    __shared__ int s[SCAN_B];
    int tid = threadIdx.x;
    int i = blockIdx.x * SCAN_B + tid;
    int v = (i < N_NODES) ? cnt[i] : 0;
    s[tid] = v;
    __syncthreads();
    for (int off = 1; off < SCAN_B; off <<= 1) {
        int t = (tid >= off) ? s[tid - off] : 0;
        __syncthreads();
        s[tid] += t;
        __syncthreads();
    }
    if (i < N_NODES) row_ptr[i] = s[tid] - v + base_off[blockIdx.x];
    if (blockIdx.x == 0 && tid == 0) row_ptr[N_NODES] = NUM_EDGES;
}

// ---------------------------------------------------------------------------
// Kernel 2: per-edge MLP fused with ATOMIC-FREE CSR scatter.
// Single 8B (src, w) pair store per edge -> half the scattered lines.
// ---------------------------------------------------------------------------
__global__ void mlp_scatter(const float* __restrict__ edge_attr,
                            const float* __restrict__ ew,
                            const float* __restrict__ w1,
                            const float* __restrict__ b1,
                            const float* __restrict__ w2,
                            const float* __restrict__ b2,
                            const int*   __restrict__ edge_index,
                            const int*   __restrict__ rank,
                            const int*   __restrict__ row_ptr,
                            int2* __restrict__ csr_pair) {
    __shared__ float w1s[8 * MLP_HID];
    __shared__ float b1s[MLP_HID];
    __shared__ float w2s[MLP_HID];
    int tid = threadIdx.x;
    if (tid < 8 * MLP_HID) w1s[tid] = w1[tid];
    if (tid < MLP_HID) { b1s[tid] = b1[tid]; w2s[tid] = w2[tid]; }
    __syncthreads();

    int e = blockIdx.x * blockDim.x + tid;
    if (e >= NUM_EDGES) return;

    float ef[8];
#pragma unroll
    for (int k = 0; k < 7; ++k) ef[k] = edge_attr[e * 7 + k];
    ef[7] = ew[e];

    float s = b2[0];
#pragma unroll
    for (int j = 0; j < MLP_HID; ++j) {
        float h = b1s[j];
#pragma unroll
        for (int k = 0; k < 8; ++k) h = fmaf(ef[k], w1s[k * MLP_HID + j], h);
        h = fmaxf(h, 0.0f);
        s = fmaf(h, w2s[j], s);
    }
    float w = 1.0f / (1.0f + expf(-s));

    int r = edge_index[e];
    int c = edge_index[NUM_EDGES + e];
    int pos = row_ptr[c] + rank[e];
    int2 pr;
    pr.x = r;
    pr.y = __float_as_int(w);
    csr_pair[pos] = pr;
}

// ---------------------------------------------------------------------------
// deg[node] = coalesced segment sum of pair.w bucket; write dinv.
// ---------------------------------------------------------------------------
__global__ void deg_dinv_csr(const int* __restrict__ row_ptr,
                             const int2* __restrict__ csr_pair,
                             float* __restrict__ dinv) {
    int t = blockIdx.x * blockDim.x + threadIdx.x;
    int node = t >> 6;
    int lane = t & 63;
    if (node >= N_NODES) return;
    int s = row_ptr[node], e = row_ptr[node + 1];
    float sum = 0.0f;
    for (int j = s + lane; j < e; j += 64) sum += __int_as_float(csr_pair[j].y);
#pragma unroll
    for (int off = 32; off > 0; off >>= 1) sum += __shfl_xor(sum, off);
    if (lane == 0)
        dinv[node] = (sum > 0.0f) ? rsqrtf(fmaxf(sum, 1e-30f)) : 0.0f;
}

// ---------------------------------------------------------------------------
// pair.w *= dinv[col] * dinv[pair.src]  (full 8B pair rewrite: fully-dirty
// lines, no write-allocate RMW)
// ---------------------------------------------------------------------------
__global__ void csr_scale(const int* __restrict__ row_ptr,
                          const float* __restrict__ dinv,
                          int2* __restrict__ csr_pair) {
    int t = blockIdx.x * blockDim.x + threadIdx.x;
    int node = t >> 6;
    int lane = t & 63;
    if (node >= N_NODES) return;
    int s = row_ptr[node], e = row_ptr[node + 1];
    float dc = dinv[node];
    for (int j = s + lane; j < e; j += 64) {
        int2 p = csr_pair[j];
        p.y = __float_as_int(__int_as_float(p.y) * dc * dinv[p.x]);
        csr_pair[j] = p;
    }
}

// ---------------------------------------------------------------------------
// build x0: bf16 only (no f32 acc stream anymore).
// ---------------------------------------------------------------------------
__global__ void init_x(const float* __restrict__ user_w,
                       const float* __restrict__ artist_w,
                       const float* __restrict__ album_w,
                       const float* __restrict__ audio,
                       const int*   __restrict__ artist_ids,
                       const int*   __restrict__ album_ids,
                       __hip_bfloat16* __restrict__ x) {
    int t = blockIdx.x * blockDim.x + threadIdx.x;
    int row = t >> 6;
    int lane = t & 63;
    if (row >= N_NODES) return;

    float v;
    if (row < NUM_USERS) {
        v = user_w[row * EMBED_DIM + lane];
    } else {
        int r = row - NUM_USERS;
        int ar = artist_ids[r];
        int al = album_ids[r];
        v = audio[r * EMBED_DIM + lane]
          + 0.5f * (artist_w[ar * EMBED_DIM + lane] + album_w[al * EMBED_DIM + lane]);
    }
    float ss = v * v;
#pragma unroll
    for (int off = 32; off > 0; off >>= 1) ss += __shfl_xor(ss, off);
    float scale = 1.0f / fmaxf(sqrtf(ss), 1e-12f);
    x[row * EMBED_DIM + lane] = __float2bfloat16(v * scale);
}

// ---------------------------------------------------------------------------
// pull-mode propagation, 8 edges x 8 dims per lane (non-final layers).
// Writes ONLY bf16 xout — no f32 acc traffic.
// ---------------------------------------------------------------------------
__global__ void propagate_mid(const int* __restrict__ row_ptr,
                              const int2* __restrict__ csr_pair,
                              const unsigned short* __restrict__ xin,
                              unsigned short* __restrict__ xout) {
    int t = blockIdx.x * blockDim.x + threadIdx.x;
    int node = t >> 6;
    int lane = t & 63;
    if (node >= N_NODES) return;

    int start = row_ptr[node];
    int end   = row_ptr[node + 1];

    int eg = lane >> 3;          // edge slot 0..7
    int dq = (lane & 7) << 3;    // dim octet start

    float a0 = 0, a1 = 0, a2 = 0, a3 = 0, a4 = 0, a5 = 0, a6 = 0, a7 = 0;

    for (int base = start; base < end; base += 8) {
        int j = base + eg;
        int src = 0; float nw = 0.0f;
        if (j < end) { int2 p = csr_pair[j]; src = p.x; nw = __int_as_float(p.y); }
        uint4 u = *(const uint4*)(xin + ((size_t)src << 6) + dq);
        a0 = fmaf(nw, __uint_as_float(u.x << 16),          a0);
        a1 = fmaf(nw, __uint_as_float(u.x & 0xffff0000u),  a1);
        a2 = fmaf(nw, __uint_as_float(u.y << 16),          a2);
        a3 = fmaf(nw, __uint_as_float(u.y & 0xffff0000u),  a3);
        a4 = fmaf(nw, __uint_as_float(u.z << 16),          a4);
        a5 = fmaf(nw, __uint_as_float(u.z & 0xffff0000u),  a5);
        a6 = fmaf(nw, __uint_as_float(u.w << 16),          a6);
        a7 = fmaf(nw, __uint_as_float(u.w & 0xffff0000u),  a7);
    }

#pragma unroll
    for (int off = 8; off <= 32; off <<= 1) {
        a0 += __shfl_xor(a0, off); a1 += __shfl_xor(a1, off);
        a2 += __shfl_xor(a2, off); a3 += __shfl_xor(a3, off);
        a4 += __shfl_xor(a4, off); a5 += __shfl_xor(a5, off);
        a6 += __shfl_xor(a6, off); a7 += __shfl_xor(a7, off);
    }

    if (eg == 0) {
        size_t o = ((size_t)node << 6) + dq;
        unsigned int b0 = (unsigned int)__bfloat16_as_ushort(__float2bfloat16(a0));
        unsigned int b1 = (unsigned int)__bfloat16_as_ushort(__float2bfloat16(a1));
        unsigned int b2 = (unsigned int)__bfloat16_as_ushort(__float2bfloat16(a2));
        unsigned int b3 = (unsigned int)__bfloat16_as_ushort(__float2bfloat16(a3));
        unsigned int b4 = (unsigned int)__bfloat16_as_ushort(__float2bfloat16(a4));
        unsigned int b5 = (unsigned int)__bfloat16_as_ushort(__float2bfloat16(a5));
        unsigned int b6 = (unsigned int)__bfloat16_as_ushort(__float2bfloat16(a6));
        unsigned int b7 = (unsigned int)__bfloat16_as_ushort(__float2bfloat16(a7));
        uint4 u;
        u.x = b0 | (b1 << 16); u.y = b2 | (b3 << 16);
        u.z = b4 | (b5 << 16); u.w = b6 | (b7 << 16);
        *(uint4*)(xout + o) = u;
    }
}

// ---------------------------------------------------------------------------
// FINAL layer: gather from x2, then out = l2norm((x0+x1+x2+a)/4), f32.
// ---------------------------------------------------------------------------
__global__ void propagate_final(const int* __restrict__ row_ptr,
                                const int2* __restrict__ csr_pair,
                                const unsigned short* __restrict__ x0,
                                const unsigned short* __restrict__ x1,
                                const unsigned short* __restrict__ x2,
                                float* __restrict__ outp) {
    int t = blockIdx.x * blockDim.x + threadIdx.x;
    int node = t >> 6;
    int lane = t & 63;
    if (node >= N_NODES) return;

    int start = row_ptr[node];
    int end   = row_ptr[node + 1];

    int eg = lane >> 3;
    int dq = (lane & 7) << 3;

    float a0 = 0, a1 = 0, a2 = 0, a3 = 0, a4 = 0, a5 = 0, a6 = 0, a7 = 0;

    for (int base = start; base < end; base += 8) {
        int j = base + eg;
        int src = 0; float nw = 0.0f;
        if (j < end) { int2 p = csr_pair[j]; src = p.x; nw = __int_as_float(p.y); }
        uint4 u = *(const uint4*)(x2 + ((size_t)src << 6) + dq);
        a0 = fmaf(nw, __uint_as_float(u.x << 16),          a0);
        a1 = fmaf(nw, __uint_as_float(u.x & 0xffff0000u),  a1);
        a2 = fmaf(nw, __uint_as_float(u.y << 16),          a2);
        a3 = fmaf(nw, __uint_as_float(u.y & 0xffff0000u),  a3);
        a4 = fmaf(nw, __uint_as_float(u.z << 16),          a4);
        a5 = fmaf(nw, __uint_as_float(u.z & 0xffff0000u),  a5);
        a6 = fmaf(nw, __uint_as_float(u.w << 16),          a6);
        a7 = fmaf(nw, __uint_as_float(u.w & 0xffff0000u),  a7);
    }

#pragma unroll
    for (int off = 8; off <= 32; off <<= 1) {
        a0 += __shfl_xor(a0, off); a1 += __shfl_xor(a1, off);
        a2 += __shfl_xor(a2, off); a3 += __shfl_xor(a3, off);
        a4 += __shfl_xor(a4, off); a5 += __shfl_xor(a5, off);
        a6 += __shfl_xor(a6, off); a7 += __shfl_xor(a7, off);
    }

    // all lanes read the three snapshots (8-way same-address broadcast)
    size_t o = ((size_t)node << 6) + dq;
    uint4 u0 = *(const uint4*)(x0 + o);
    uint4 u1 = *(const uint4*)(x1 + o);
    uint4 u2 = *(const uint4*)(x2 + o);

#define BF_LO(u) __uint_as_float((u) << 16)
#define BF_HI(u) __uint_as_float((u) & 0xffff0000u)
    float v0 = (BF_LO(u0.x) + BF_LO(u1.x) + BF_LO(u2.x) + a0) * 0.25f;
    float v1 = (BF_HI(u0.x) + BF_HI(u1.x) + BF_HI(u2.x) + a1) * 0.25f;
    float v2 = (BF_LO(u0.y) + BF_LO(u1.y) + BF_LO(u2.y) + a2) * 0.25f;
    float v3 = (BF_HI(u0.y) + BF_HI(u1.y) + BF_HI(u2.y) + a3) * 0.25f;
    float v4 = (BF_LO(u0.z) + BF_LO(u1.z) + BF_LO(u2.z) + a4) * 0.25f;
    float v5 = (BF_HI(u0.z) + BF_HI(u1.z) + BF_HI(u2.z) + a5) * 0.25f;
    float v6 = (BF_LO(u0.w) + BF_LO(u1.w) + BF_LO(u2.w) + a6) * 0.25f;
    float v7 = (BF_HI(u0.w) + BF_HI(u1.w) + BF_HI(u2.w) + a7) * 0.25f;
#undef BF_LO
#undef BF_HI

    float ss = v0*v0 + v1*v1 + v2*v2 + v3*v3 + v4*v4 + v5*v5 + v6*v6 + v7*v7;
#pragma unroll
    for (int off = 1; off <= 4; off <<= 1) ss += __shfl_xor(ss, off);
    float scale = 1.0f / fmaxf(sqrtf(ss), 1e-12f);

    if (eg == 0) {
        float4 r0 = { v0*scale, v1*scale, v2*scale, v3*scale };
        float4 r1 = { v4*scale, v5*scale, v6*scale, v7*scale };
        float4* wp = (float4*)(outp + o);
        wp[0] = r0; wp[1] = r1;
    }
    if (blockIdx.x == 0 && threadIdx.x == 0)
        outp[(size_t)N_NODES * EMBED_DIM] = 0.0f;  // align_loss
}

// ---------------------------------------------------------------------------
extern "C" void kernel_launch(void* const* d_in, const int* in_sizes, int n_in,
                              void* d_out, int out_size, void* d_ws, size_t ws_size,
                              hipStream_t stream) {
    const float* user_w     = (const float*)d_in[0];
    const float* artist_w   = (const float*)d_in[1];
    const float* album_w    = (const float*)d_in[2];
    const float* audio      = (const float*)d_in[3];
    const float* edge_attr  = (const float*)d_in[4];
    const float* ew         = (const float*)d_in[5];
    const float* w1         = (const float*)d_in[6];
    const float* b1         = (const float*)d_in[7];
    const float* w2         = (const float*)d_in[8];
    const float* b2         = (const float*)d_in[9];
    const int*   edge_index = (const int*)d_in[10];
    const int*   artist_ids = (const int*)d_in[11];
    const int*   album_ids  = (const int*)d_in[12];
    float* out = (float*)d_out;

    float* ws = (float*)d_ws;
    // Persistent regions (offsets in float units):
    unsigned short* x0 = (unsigned short*)ws;                // 9.6M bf16
    unsigned short* x1 = (unsigned short*)(ws + 4800000);    // 9.6M bf16
    unsigned short* x2 = (unsigned short*)(ws + 9600000);    // 9.6M bf16
    int*  row_ptr  = (int*)(ws + 14400000);                  // 150001 ints
    int2* csr_pair = (int2*)(ws + 14560000);                 // 1.25M pairs (8B-aligned)
    float* dinv    = ws + 17060000;                          // 150k floats
    // Transients aliased into x0/x1 region (dead before init_x writes x0):
    int*   cnt     = (int*)ws;                               // 150k ints
    int*   rank    = (int*)(ws + 150000);                    // 1.25M ints
    int*   part    = (int*)(ws + 1400000);                   // 147 ints
    int*   baseoff = (int*)(ws + 1401000);                   // 147 ints

    const int B = 256;
    const int egrid = (NUM_EDGES + B - 1) / B;
    const int ngrid = (N_NODES * EMBED_DIM) / B;  // wave-per-node grids

    hipMemsetAsync(cnt, 0, N_NODES * sizeof(int), stream);

    hist_rank<<<egrid, B, 0, stream>>>(edge_index, cnt, rank);

    scan_partial<<<SCAN_NB, SCAN_B, 0, stream>>>(cnt, part);
    scan_offsets<<<1, 256, 0, stream>>>(part, baseoff);
    scan_apply<<<SCAN_NB, SCAN_B, 0, stream>>>(cnt, baseoff, row_ptr);

    mlp_scatter<<<egrid, B, 0, stream>>>(
        edge_attr, ew, w1, b1, w2, b2, edge_index, rank, row_ptr, csr_pair);

    deg_dinv_csr<<<ngrid, B, 0, stream>>>(row_ptr, csr_pair, dinv);
    csr_scale<<<ngrid, B, 0, stream>>>(row_ptr, dinv, csr_pair);

    init_x<<<ngrid, B, 0, stream>>>(
        user_w, artist_w, album_w, audio, artist_ids, album_ids,
        (__hip_bfloat16*)x0);

    propagate_mid<<<ngrid, B, 0, stream>>>(row_ptr, csr_pair, x0, x1);
    propagate_mid<<<ngrid, B, 0, stream>>>(row_ptr, csr_pair, x1, x2);
    propagate_final<<<ngrid, B, 0, stream>>>(row_ptr, csr_pair, x0, x1, x2, out);
}